// Round 1
// baseline (206.975 us; speedup 1.0000x reference)
//
#include <hip/hip_runtime.h>

#define BB 32
#define NN 1024
#define FIN 64
#define HH 24
#define MS 8
#define MCHUNK (NN / MS)   // 128

// ---------------- kernel 1: Z = relu(xt @ W + b), plus transposed copy ----------------
__global__ void k_z(const float* __restrict__ xt, const float* __restrict__ W,
                    const float* __restrict__ bias,
                    float* __restrict__ Z, float* __restrict__ Zt) {
    __shared__ float Wl[FIN * HH];
    int t = threadIdx.x;
    for (int i = t; i < FIN * HH; i += 256) Wl[i] = W[i];
    __syncthreads();

    int row = blockIdx.x * 256 + t;      // b*N + n
    int b = row >> 10, n = row & (NN - 1);

    const float* xr = xt + (size_t)row * FIN;
    float x[FIN];
    #pragma unroll
    for (int k4 = 0; k4 < FIN / 4; ++k4) {
        float4 v = reinterpret_cast<const float4*>(xr)[k4];
        x[4 * k4 + 0] = v.x; x[4 * k4 + 1] = v.y;
        x[4 * k4 + 2] = v.z; x[4 * k4 + 3] = v.w;
    }

    float z[HH];
    #pragma unroll
    for (int hg = 0; hg < HH / 4; ++hg) {
        float4 acc = reinterpret_cast<const float4*>(bias)[hg];
        #pragma unroll
        for (int k = 0; k < FIN; ++k) {
            float4 w = *reinterpret_cast<const float4*>(&Wl[k * HH + hg * 4]);
            acc.x += x[k] * w.x; acc.y += x[k] * w.y;
            acc.z += x[k] * w.z; acc.w += x[k] * w.w;
        }
        z[hg * 4 + 0] = fmaxf(acc.x, 0.f);
        z[hg * 4 + 1] = fmaxf(acc.y, 0.f);
        z[hg * 4 + 2] = fmaxf(acc.z, 0.f);
        z[hg * 4 + 3] = fmaxf(acc.w, 0.f);
    }

    float* zr = Z + (size_t)row * HH;
    #pragma unroll
    for (int hg = 0; hg < HH / 4; ++hg)
        reinterpret_cast<float4*>(zr)[hg] =
            make_float4(z[4 * hg], z[4 * hg + 1], z[4 * hg + 2], z[4 * hg + 3]);

    #pragma unroll
    for (int h = 0; h < HH; ++h)
        Zt[((size_t)b * HH + h) * NN + n] = z[h];   // coalesced across lanes
}

// ---------------- kernel 2: row max/sum partials over m-chunks ----------------
__global__ void k_rowstats(const float* __restrict__ Z,
                           float* __restrict__ pmax, float* __restrict__ psum) {
    int t = threadIdx.x;
    int b = blockIdx.z;
    int n = blockIdx.x * 128 + t;
    int mb = blockIdx.y * MCHUNK;

    __shared__ float Zs[MCHUNK * HH];
    const float* src = Z + ((size_t)b * NN + mb) * HH;
    for (int i = t; i < MCHUNK * HH / 4; i += 128)
        reinterpret_cast<float4*>(Zs)[i] = reinterpret_cast<const float4*>(src)[i];
    __syncthreads();

    float zn[HH];
    const float* zr = Z + ((size_t)b * NN + n) * HH;
    #pragma unroll
    for (int i = 0; i < HH / 4; ++i) {
        float4 v = reinterpret_cast<const float4*>(zr)[i];
        zn[4 * i + 0] = v.x; zn[4 * i + 1] = v.y;
        zn[4 * i + 2] = v.z; zn[4 * i + 3] = v.w;
    }

    float mx = -INFINITY, s = 0.f;
    for (int mm = 0; mm < MCHUNK; ++mm) {
        const float4* zp = reinterpret_cast<const float4*>(&Zs[mm * HH]);
        float a = 0.f;
        #pragma unroll
        for (int i = 0; i < HH / 4; ++i) {
            float4 v = zp[i];
            a += zn[4 * i + 0] * v.x + zn[4 * i + 1] * v.y
               + zn[4 * i + 2] * v.z + zn[4 * i + 3] * v.w;
        }
        float nm = fmaxf(mx, a);
        s = s * __expf(mx - nm) + __expf(a - nm);
        mx = nm;
    }
    size_t o = ((size_t)b * MS + blockIdx.y) * NN + n;
    pmax[o] = mx;
    psum[o] = s;
}

// ---------------- kernel 2b: combine row partials ----------------
__global__ void k_rowcombine(const float* __restrict__ pmax, const float* __restrict__ psum,
                             float* __restrict__ rowmax, float* __restrict__ rinv) {
    int i = blockIdx.x * 256 + threadIdx.x;   // b*N + n
    int b = i >> 10, n = i & (NN - 1);
    float M = -INFINITY;
    #pragma unroll
    for (int j = 0; j < MS; ++j)
        M = fmaxf(M, pmax[((size_t)b * MS + j) * NN + n]);
    float s = 0.f;
    #pragma unroll
    for (int j = 0; j < MS; ++j) {
        size_t o = ((size_t)b * MS + j) * NN + n;
        s += psum[o] * __expf(pmax[o] - M);
    }
    rowmax[i] = M;
    rinv[i] = 1.0f / s;
}

// ---------------- kernel 3: column-sum of S partials ----------------
__global__ void k_colsum(const float* __restrict__ Z, const float* __restrict__ rowmax,
                         const float* __restrict__ rinv, float* __restrict__ pcol) {
    int t = threadIdx.x;
    int b = blockIdx.z;
    int n = blockIdx.x * 128 + t;
    int mb = blockIdx.y * MCHUNK;

    __shared__ float Zs[MCHUNK * HH];
    __shared__ float rmS[MCHUNK], riS[MCHUNK];
    const float* src = Z + ((size_t)b * NN + mb) * HH;
    for (int i = t; i < MCHUNK * HH / 4; i += 128)
        reinterpret_cast<float4*>(Zs)[i] = reinterpret_cast<const float4*>(src)[i];
    rmS[t] = rowmax[(size_t)b * NN + mb + t];
    riS[t] = rinv[(size_t)b * NN + mb + t];
    __syncthreads();

    float zn[HH];
    const float* zr = Z + ((size_t)b * NN + n) * HH;
    #pragma unroll
    for (int i = 0; i < HH / 4; ++i) {
        float4 v = reinterpret_cast<const float4*>(zr)[i];
        zn[4 * i + 0] = v.x; zn[4 * i + 1] = v.y;
        zn[4 * i + 2] = v.z; zn[4 * i + 3] = v.w;
    }

    float c = 0.f;
    for (int mm = 0; mm < MCHUNK; ++mm) {
        const float4* zp = reinterpret_cast<const float4*>(&Zs[mm * HH]);
        float a = 0.f;
        #pragma unroll
        for (int i = 0; i < HH / 4; ++i) {
            float4 v = zp[i];
            a += zn[4 * i + 0] * v.x + zn[4 * i + 1] * v.y
               + zn[4 * i + 2] * v.z + zn[4 * i + 3] * v.w;
        }
        c += __expf(a - rmS[mm]) * riS[mm];   // S[m,n] term (A symmetric)
    }
    pcol[((size_t)b * MS + blockIdx.y) * NN + n] = c;
}

// ---------------- kernel 3b: degree -> dinv ----------------
__global__ void k_dinv(const float* __restrict__ pcol, float* __restrict__ dinv) {
    int i = blockIdx.x * 256 + threadIdx.x;
    int b = i >> 10, n = i & (NN - 1);
    float c = 0.f;
    #pragma unroll
    for (int j = 0; j < MS; ++j)
        c += pcol[((size_t)b * MS + j) * NN + n];
    float degree = 1.5f + 0.5f * c;           // always >= 1.5, clip is a no-op
    dinv[i] = rsqrtf(degree);
}

// ---------------- kernel 4: final output ----------------
#define RB 16
#define K4C 256
__global__ __launch_bounds__(256) void k_out(
    const float* __restrict__ Z, const float* __restrict__ Zt,
    const float* __restrict__ rowmax, const float* __restrict__ rinv,
    const float* __restrict__ dinv, float* __restrict__ out) {
    __shared__ float Zs[HH][K4C];
    __shared__ float rmS[K4C], riS[K4C], dvS[K4C];

    int t = threadIdx.x, lane = t & 63, w = t >> 6;
    int b = blockIdx.y;
    int n0 = blockIdx.x * RB;

    // this wave's 4 rows: registers
    float zn[4][HH];
    float rm_n[4], ri_n[4], dv_n[4];
    int nrow[4];
    #pragma unroll
    for (int r = 0; r < 4; ++r) {
        int n = n0 + w * 4 + r;
        nrow[r] = n;
        const float* zr = Z + ((size_t)b * NN + n) * HH;
        #pragma unroll
        for (int i = 0; i < HH / 4; ++i) {
            float4 v = reinterpret_cast<const float4*>(zr)[i];
            zn[r][4 * i + 0] = v.x; zn[r][4 * i + 1] = v.y;
            zn[r][4 * i + 2] = v.z; zn[r][4 * i + 3] = v.w;
        }
        rm_n[r] = rowmax[(size_t)b * NN + n];
        ri_n[r] = rinv[(size_t)b * NN + n];
        dv_n[r] = dinv[(size_t)b * NN + n];
    }

    for (int mc = 0; mc < NN; mc += K4C) {
        __syncthreads();
        // stage Zt chunk [24][256] (coalesced) + per-m stats
        for (int i = t; i < HH * K4C / 4; i += 256) {
            int h = i >> 6, p = i & 63;
            reinterpret_cast<float4*>(&Zs[h][0])[p] =
                reinterpret_cast<const float4*>(Zt + ((size_t)b * HH + h) * NN + mc)[p];
        }
        if (t < K4C) {
            rmS[t] = rowmax[(size_t)b * NN + mc + t];
            riS[t] = rinv[(size_t)b * NN + mc + t];
            dvS[t] = dinv[(size_t)b * NN + mc + t];
        }
        __syncthreads();

        #pragma unroll
        for (int j = 0; j < K4C / 64; ++j) {
            int ml = j * 64 + lane;
            int m = mc + ml;
            float acc0 = 0.f, acc1 = 0.f, acc2 = 0.f, acc3 = 0.f;
            #pragma unroll
            for (int h = 0; h < HH; ++h) {
                float zm = Zs[h][ml];     // stride-1 lanes: conflict-free
                acc0 += zn[0][h] * zm;
                acc1 += zn[1][h] * zm;
                acc2 += zn[2][h] * zm;
                acc3 += zn[3][h] * zm;
            }
            float rmm = rmS[ml], rim = riS[ml], dvm = dvS[ml];
            {
                float v = 0.5f * (__expf(acc0 - rm_n[0]) * ri_n[0] + __expf(acc0 - rmm) * rim);
                if (m == nrow[0]) v += 1.0f;
                out[((size_t)b * NN + nrow[0]) * NN + m] = v * dv_n[0] * dvm;
            }
            {
                float v = 0.5f * (__expf(acc1 - rm_n[1]) * ri_n[1] + __expf(acc1 - rmm) * rim);
                if (m == nrow[1]) v += 1.0f;
                out[((size_t)b * NN + nrow[1]) * NN + m] = v * dv_n[1] * dvm;
            }
            {
                float v = 0.5f * (__expf(acc2 - rm_n[2]) * ri_n[2] + __expf(acc2 - rmm) * rim);
                if (m == nrow[2]) v += 1.0f;
                out[((size_t)b * NN + nrow[2]) * NN + m] = v * dv_n[2] * dvm;
            }
            {
                float v = 0.5f * (__expf(acc3 - rm_n[3]) * ri_n[3] + __expf(acc3 - rmm) * rim);
                if (m == nrow[3]) v += 1.0f;
                out[((size_t)b * NN + nrow[3]) * NN + m] = v * dv_n[3] * dvm;
            }
        }
    }
}

extern "C" void kernel_launch(void* const* d_in, const int* in_sizes, int n_in,
                              void* d_out, int out_size, void* d_ws, size_t ws_size,
                              hipStream_t stream) {
    const float* xt   = (const float*)d_in[0];
    const float* W    = (const float*)d_in[1];
    const float* bias = (const float*)d_in[2];
    float* out = (float*)d_out;
    float* ws  = (float*)d_ws;

    const size_t Z_OFF    = 0;
    const size_t ZT_OFF   = Z_OFF  + (size_t)BB * NN * HH;       // 786432
    const size_t RM_OFF   = ZT_OFF + (size_t)BB * HH * NN;       // +786432
    const size_t RI_OFF   = RM_OFF + (size_t)BB * NN;
    const size_t DV_OFF   = RI_OFF + (size_t)BB * NN;
    const size_t PMAX_OFF = DV_OFF + (size_t)BB * NN;
    const size_t PSUM_OFF = PMAX_OFF + (size_t)BB * MS * NN;
    const size_t PCOL_OFF = PSUM_OFF + (size_t)BB * MS * NN;

    float* Z      = ws + Z_OFF;
    float* Zt     = ws + ZT_OFF;
    float* rowmax = ws + RM_OFF;
    float* rinv   = ws + RI_OFF;
    float* dinv   = ws + DV_OFF;
    float* pmax   = ws + PMAX_OFF;
    float* psum   = ws + PSUM_OFF;
    float* pcol   = ws + PCOL_OFF;

    k_z<<<dim3(BB * NN / 256), dim3(256), 0, stream>>>(xt, W, bias, Z, Zt);
    k_rowstats<<<dim3(NN / 128, MS, BB), dim3(128), 0, stream>>>(Z, pmax, psum);
    k_rowcombine<<<dim3(BB * NN / 256), dim3(256), 0, stream>>>(pmax, psum, rowmax, rinv);
    k_colsum<<<dim3(NN / 128, MS, BB), dim3(128), 0, stream>>>(Z, rowmax, rinv, pcol);
    k_dinv<<<dim3(BB * NN / 256), dim3(256), 0, stream>>>(pcol, dinv);
    k_out<<<dim3(NN / RB, BB), dim3(256), 0, stream>>>(Z, Zt, rowmax, rinv, dinv, out);
}

// Round 2
// 185.085 us; speedup vs baseline: 1.1183x; 1.1183x over previous
//
#include <hip/hip_runtime.h>

#define BB 32
#define NN 1024
#define FIN 64
#define HH 24

// ---------------- kernel 1: Z = relu(xt @ W + b), plus transposed copy ----------------
__global__ void k_z(const float* __restrict__ xt, const float* __restrict__ W,
                    const float* __restrict__ bias,
                    float* __restrict__ Z, float* __restrict__ Zt) {
    __shared__ float Wl[FIN * HH];
    int t = threadIdx.x;
    for (int i = t; i < FIN * HH; i += 256) Wl[i] = W[i];
    __syncthreads();

    int row = blockIdx.x * 256 + t;      // b*N + n
    int b = row >> 10, n = row & (NN - 1);

    const float* xr = xt + (size_t)row * FIN;
    float x[FIN];
    #pragma unroll
    for (int k4 = 0; k4 < FIN / 4; ++k4) {
        float4 v = reinterpret_cast<const float4*>(xr)[k4];
        x[4 * k4 + 0] = v.x; x[4 * k4 + 1] = v.y;
        x[4 * k4 + 2] = v.z; x[4 * k4 + 3] = v.w;
    }

    float z[HH];
    #pragma unroll
    for (int hg = 0; hg < HH / 4; ++hg) {
        float4 acc = reinterpret_cast<const float4*>(bias)[hg];
        #pragma unroll
        for (int k = 0; k < FIN; ++k) {
            float4 w = *reinterpret_cast<const float4*>(&Wl[k * HH + hg * 4]);
            acc.x += x[k] * w.x; acc.y += x[k] * w.y;
            acc.z += x[k] * w.z; acc.w += x[k] * w.w;
        }
        z[hg * 4 + 0] = fmaxf(acc.x, 0.f);
        z[hg * 4 + 1] = fmaxf(acc.y, 0.f);
        z[hg * 4 + 2] = fmaxf(acc.z, 0.f);
        z[hg * 4 + 3] = fmaxf(acc.w, 0.f);
    }

    float* zr = Z + (size_t)row * HH;
    #pragma unroll
    for (int hg = 0; hg < HH / 4; ++hg)
        reinterpret_cast<float4*>(zr)[hg] =
            make_float4(z[4 * hg], z[4 * hg + 1], z[4 * hg + 2], z[4 * hg + 3]);

    #pragma unroll
    for (int h = 0; h < HH; ++h)
        Zt[((size_t)b * HH + h) * NN + n] = z[h];   // coalesced across lanes
}

// ---------------- kernel 2: full-row softmax stats (max, 1/sum) ----------------
// 256 threads = 4 waves; each wave owns 8 n-rows (in registers), sweeps all m
// with m = lane-strided coalesced global loads. No LDS in the hot loop.
__global__ __launch_bounds__(256, 2) void k_rowstats(
        const float* __restrict__ Z,
        float* __restrict__ rowmax, float* __restrict__ rinv) {
    int t = threadIdx.x, lane = t & 63, w = t >> 6;
    int b = blockIdx.y;
    int n0 = blockIdx.x * 32 + w * 8;
    const float* Zb = Z + (size_t)b * NN * HH;

    float zn[8][HH];
    #pragma unroll
    for (int r = 0; r < 8; ++r) {
        const float4* zr = reinterpret_cast<const float4*>(Zb + (size_t)(n0 + r) * HH);
        #pragma unroll
        for (int i = 0; i < HH / 4; ++i) {
            float4 v = zr[i];
            zn[r][4 * i + 0] = v.x; zn[r][4 * i + 1] = v.y;
            zn[r][4 * i + 2] = v.z; zn[r][4 * i + 3] = v.w;
        }
    }

    float mx[8], s[8];
    #pragma unroll
    for (int r = 0; r < 8; ++r) { mx[r] = -1e30f; s[r] = 0.f; }

    for (int mj = 0; mj < NN; mj += 64) {
        const float4* zmp = reinterpret_cast<const float4*>(Zb + (size_t)(mj + lane) * HH);
        float zm[HH];
        #pragma unroll
        for (int i = 0; i < HH / 4; ++i)
            *reinterpret_cast<float4*>(&zm[4 * i]) = zmp[i];

        #pragma unroll
        for (int r = 0; r < 8; ++r) {
            float a = 0.f;
            #pragma unroll
            for (int h = 0; h < HH; ++h) a += zn[r][h] * zm[h];
            float nm = fmaxf(mx[r], a);
            s[r] = s[r] * __expf(mx[r] - nm) + __expf(a - nm);
            mx[r] = nm;
        }
    }

    // 64-lane butterfly combine of (max, sum)
    #pragma unroll
    for (int off = 1; off < 64; off <<= 1) {
        #pragma unroll
        for (int r = 0; r < 8; ++r) {
            float om = __shfl_xor(mx[r], off, 64);
            float os = __shfl_xor(s[r], off, 64);
            float nm = fmaxf(mx[r], om);
            s[r] = s[r] * __expf(mx[r] - nm) + os * __expf(om - nm);
            mx[r] = nm;
        }
    }
    if (lane == 0) {
        #pragma unroll
        for (int r = 0; r < 8; ++r) {
            rowmax[(size_t)b * NN + n0 + r] = mx[r];
            rinv[(size_t)b * NN + n0 + r] = 1.0f / s[r];
        }
    }
}

// ---------------- kernel 3: colsum of S -> dinv directly ----------------
__global__ __launch_bounds__(256, 2) void k_colsum(
        const float* __restrict__ Z, const float* __restrict__ rowmax,
        const float* __restrict__ rinv, float* __restrict__ dinv) {
    int t = threadIdx.x, lane = t & 63, w = t >> 6;
    int b = blockIdx.y;
    int n0 = blockIdx.x * 32 + w * 8;
    const float* Zb = Z + (size_t)b * NN * HH;

    float zn[8][HH];
    #pragma unroll
    for (int r = 0; r < 8; ++r) {
        const float4* zr = reinterpret_cast<const float4*>(Zb + (size_t)(n0 + r) * HH);
        #pragma unroll
        for (int i = 0; i < HH / 4; ++i) {
            float4 v = zr[i];
            zn[r][4 * i + 0] = v.x; zn[r][4 * i + 1] = v.y;
            zn[r][4 * i + 2] = v.z; zn[r][4 * i + 3] = v.w;
        }
    }

    float c[8];
    #pragma unroll
    for (int r = 0; r < 8; ++r) c[r] = 0.f;

    for (int mj = 0; mj < NN; mj += 64) {
        int m = mj + lane;
        const float4* zmp = reinterpret_cast<const float4*>(Zb + (size_t)m * HH);
        float zm[HH];
        #pragma unroll
        for (int i = 0; i < HH / 4; ++i)
            *reinterpret_cast<float4*>(&zm[4 * i]) = zmp[i];
        float rm = rowmax[(size_t)b * NN + m];
        float ri = rinv[(size_t)b * NN + m];

        #pragma unroll
        for (int r = 0; r < 8; ++r) {
            float a = 0.f;
            #pragma unroll
            for (int h = 0; h < HH; ++h) a += zn[r][h] * zm[h];
            c[r] += __expf(a - rm) * ri;    // S[m, n0+r]
        }
    }

    #pragma unroll
    for (int off = 1; off < 64; off <<= 1) {
        #pragma unroll
        for (int r = 0; r < 8; ++r)
            c[r] += __shfl_xor(c[r], off, 64);
    }
    if (lane == 0) {
        #pragma unroll
        for (int r = 0; r < 8; ++r) {
            float degree = 1.5f + 0.5f * c[r];   // >= 1.5, clip is a no-op
            dinv[(size_t)b * NN + n0 + r] = rsqrtf(degree);
        }
    }
}

// ---------------- kernel 4: final output ----------------
#define RB 16
#define K4C 256
__global__ __launch_bounds__(256) void k_out(
    const float* __restrict__ Z, const float* __restrict__ Zt,
    const float* __restrict__ rowmax, const float* __restrict__ rinv,
    const float* __restrict__ dinv, float* __restrict__ out) {
    __shared__ float Zs[HH][K4C];
    __shared__ float rmS[K4C], riS[K4C], dvS[K4C];

    int t = threadIdx.x, lane = t & 63, w = t >> 6;
    int b = blockIdx.y;
    int n0 = blockIdx.x * RB;

    float zn[4][HH];
    float rm_n[4], ri_n[4], dv_n[4];
    int nrow[4];
    #pragma unroll
    for (int r = 0; r < 4; ++r) {
        int n = n0 + w * 4 + r;
        nrow[r] = n;
        const float* zr = Z + ((size_t)b * NN + n) * HH;
        #pragma unroll
        for (int i = 0; i < HH / 4; ++i) {
            float4 v = reinterpret_cast<const float4*>(zr)[i];
            zn[r][4 * i + 0] = v.x; zn[r][4 * i + 1] = v.y;
            zn[r][4 * i + 2] = v.z; zn[r][4 * i + 3] = v.w;
        }
        rm_n[r] = rowmax[(size_t)b * NN + n];
        ri_n[r] = rinv[(size_t)b * NN + n];
        dv_n[r] = dinv[(size_t)b * NN + n];
    }

    for (int mc = 0; mc < NN; mc += K4C) {
        __syncthreads();
        for (int i = t; i < HH * K4C / 4; i += 256) {
            int h = i >> 6, p = i & 63;
            reinterpret_cast<float4*>(&Zs[h][0])[p] =
                reinterpret_cast<const float4*>(Zt + ((size_t)b * HH + h) * NN + mc)[p];
        }
        if (t < K4C) {
            rmS[t] = rowmax[(size_t)b * NN + mc + t];
            riS[t] = rinv[(size_t)b * NN + mc + t];
            dvS[t] = dinv[(size_t)b * NN + mc + t];
        }
        __syncthreads();

        #pragma unroll
        for (int j = 0; j < K4C / 64; ++j) {
            int ml = j * 64 + lane;
            int m = mc + ml;
            float acc0 = 0.f, acc1 = 0.f, acc2 = 0.f, acc3 = 0.f;
            #pragma unroll
            for (int h = 0; h < HH; ++h) {
                float zm = Zs[h][ml];
                acc0 += zn[0][h] * zm;
                acc1 += zn[1][h] * zm;
                acc2 += zn[2][h] * zm;
                acc3 += zn[3][h] * zm;
            }
            float rmm = rmS[ml], rim = riS[ml], dvm = dvS[ml];
            {
                float v = 0.5f * (__expf(acc0 - rm_n[0]) * ri_n[0] + __expf(acc0 - rmm) * rim);
                if (m == nrow[0]) v += 1.0f;
                out[((size_t)b * NN + nrow[0]) * NN + m] = v * dv_n[0] * dvm;
            }
            {
                float v = 0.5f * (__expf(acc1 - rm_n[1]) * ri_n[1] + __expf(acc1 - rmm) * rim);
                if (m == nrow[1]) v += 1.0f;
                out[((size_t)b * NN + nrow[1]) * NN + m] = v * dv_n[1] * dvm;
            }
            {
                float v = 0.5f * (__expf(acc2 - rm_n[2]) * ri_n[2] + __expf(acc2 - rmm) * rim);
                if (m == nrow[2]) v += 1.0f;
                out[((size_t)b * NN + nrow[2]) * NN + m] = v * dv_n[2] * dvm;
            }
            {
                float v = 0.5f * (__expf(acc3 - rm_n[3]) * ri_n[3] + __expf(acc3 - rmm) * rim);
                if (m == nrow[3]) v += 1.0f;
                out[((size_t)b * NN + nrow[3]) * NN + m] = v * dv_n[3] * dvm;
            }
        }
    }
}

extern "C" void kernel_launch(void* const* d_in, const int* in_sizes, int n_in,
                              void* d_out, int out_size, void* d_ws, size_t ws_size,
                              hipStream_t stream) {
    const float* xt   = (const float*)d_in[0];
    const float* W    = (const float*)d_in[1];
    const float* bias = (const float*)d_in[2];
    float* out = (float*)d_out;
    float* ws  = (float*)d_ws;

    const size_t Z_OFF  = 0;
    const size_t ZT_OFF = Z_OFF  + (size_t)BB * NN * HH;
    const size_t RM_OFF = ZT_OFF + (size_t)BB * HH * NN;
    const size_t RI_OFF = RM_OFF + (size_t)BB * NN;
    const size_t DV_OFF = RI_OFF + (size_t)BB * NN;

    float* Z      = ws + Z_OFF;
    float* Zt     = ws + ZT_OFF;
    float* rowmax = ws + RM_OFF;
    float* rinv   = ws + RI_OFF;
    float* dinv   = ws + DV_OFF;

    k_z<<<dim3(BB * NN / 256), dim3(256), 0, stream>>>(xt, W, bias, Z, Zt);
    k_rowstats<<<dim3(NN / 32, BB), dim3(256), 0, stream>>>(Z, rowmax, rinv);
    k_colsum<<<dim3(NN / 32, BB), dim3(256), 0, stream>>>(Z, rowmax, rinv, dinv);
    k_out<<<dim3(NN / RB, BB), dim3(256), 0, stream>>>(Z, Zt, rowmax, rinv, dinv, out);
}

// Round 3
// 174.569 us; speedup vs baseline: 1.1856x; 1.0602x over previous
//
#include <hip/hip_runtime.h>

#define BB 32
#define NN 1024
#define FIN 64
#define HH 24
#define LN2F 0.6931471805599453f

// ---------------- kernel 1: Z = relu(xt @ W + b) (raw), plus transposed copy ----------------
__global__ void k_z(const float* __restrict__ xt, const float* __restrict__ W,
                    const float* __restrict__ bias,
                    float* __restrict__ Z, float* __restrict__ Zt) {
    __shared__ float Wl[FIN * HH];
    int t = threadIdx.x;
    for (int i = t; i < FIN * HH; i += 256) Wl[i] = W[i];
    __syncthreads();

    int row = blockIdx.x * 256 + t;      // b*N + n
    int b = row >> 10, n = row & (NN - 1);

    const float* xr = xt + (size_t)row * FIN;
    float x[FIN];
    #pragma unroll
    for (int k4 = 0; k4 < FIN / 4; ++k4) {
        float4 v = reinterpret_cast<const float4*>(xr)[k4];
        x[4 * k4 + 0] = v.x; x[4 * k4 + 1] = v.y;
        x[4 * k4 + 2] = v.z; x[4 * k4 + 3] = v.w;
    }

    float z[HH];
    #pragma unroll
    for (int hg = 0; hg < HH / 4; ++hg) {
        float4 acc = reinterpret_cast<const float4*>(bias)[hg];
        #pragma unroll
        for (int k = 0; k < FIN; ++k) {
            float4 w = *reinterpret_cast<const float4*>(&Wl[k * HH + hg * 4]);
            acc.x += x[k] * w.x; acc.y += x[k] * w.y;
            acc.z += x[k] * w.z; acc.w += x[k] * w.w;
        }
        z[hg * 4 + 0] = fmaxf(acc.x, 0.f);
        z[hg * 4 + 1] = fmaxf(acc.y, 0.f);
        z[hg * 4 + 2] = fmaxf(acc.z, 0.f);
        z[hg * 4 + 3] = fmaxf(acc.w, 0.f);
    }

    float* zr = Z + (size_t)row * HH;
    #pragma unroll
    for (int hg = 0; hg < HH / 4; ++hg)
        reinterpret_cast<float4*>(zr)[hg] =
            make_float4(z[4 * hg], z[4 * hg + 1], z[4 * hg + 2], z[4 * hg + 3]);

    #pragma unroll
    for (int h = 0; h < HH; ++h)
        Zt[((size_t)b * HH + h) * NN + n] = z[h];   // coalesced across lanes
}

// ---------------- kernel 2: lse[n] = log(sum_m exp(<Zn,Zm>)) ----------------
// No max-subtraction needed: dots are in [0, ~40] (Z >= 0), sum <= 1024*e^40 << fp32 max.
// 4 waves/block; each wave owns 8 n-rows in registers, m lane-strided from global (L2).
__global__ __launch_bounds__(256, 2) void k_rowsum(
        const float* __restrict__ Z, float* __restrict__ lse) {
    int t = threadIdx.x, lane = t & 63, w = t >> 6;
    int b = blockIdx.y;
    int n0 = blockIdx.x * 32 + w * 8;
    const float* Zb = Z + (size_t)b * NN * HH;

    float zn[8][HH];
    #pragma unroll
    for (int r = 0; r < 8; ++r) {
        const float4* zr = reinterpret_cast<const float4*>(Zb + (size_t)(n0 + r) * HH);
        #pragma unroll
        for (int i = 0; i < HH / 4; ++i) {
            float4 v = zr[i];
            zn[r][4 * i + 0] = v.x; zn[r][4 * i + 1] = v.y;
            zn[r][4 * i + 2] = v.z; zn[r][4 * i + 3] = v.w;
        }
    }

    float s[8];
    #pragma unroll
    for (int r = 0; r < 8; ++r) s[r] = 0.f;

    for (int mj = 0; mj < NN; mj += 64) {
        const float4* zmp = reinterpret_cast<const float4*>(Zb + (size_t)(mj + lane) * HH);
        float zm[HH];
        #pragma unroll
        for (int i = 0; i < HH / 4; ++i)
            *reinterpret_cast<float4*>(&zm[4 * i]) = zmp[i];

        #pragma unroll
        for (int r = 0; r < 8; ++r) {
            float a = 0.f;
            #pragma unroll
            for (int h = 0; h < HH; ++h) a += zn[r][h] * zm[h];
            s[r] += __expf(a);
        }
    }

    #pragma unroll
    for (int off = 1; off < 64; off <<= 1) {
        #pragma unroll
        for (int r = 0; r < 8; ++r)
            s[r] += __shfl_xor(s[r], off, 64);
    }
    if (lane == 0) {
        #pragma unroll
        for (int r = 0; r < 8; ++r)
            lse[(size_t)b * NN + n0 + r] = __logf(s[r]);
    }
}

// ---------------- kernel 3: colsum of S -> dinv ----------------
__global__ __launch_bounds__(256, 2) void k_colsum(
        const float* __restrict__ Z, const float* __restrict__ lse,
        float* __restrict__ dinv) {
    int t = threadIdx.x, lane = t & 63, w = t >> 6;
    int b = blockIdx.y;
    int n0 = blockIdx.x * 32 + w * 8;
    const float* Zb = Z + (size_t)b * NN * HH;

    float zn[8][HH];
    #pragma unroll
    for (int r = 0; r < 8; ++r) {
        const float4* zr = reinterpret_cast<const float4*>(Zb + (size_t)(n0 + r) * HH);
        #pragma unroll
        for (int i = 0; i < HH / 4; ++i) {
            float4 v = zr[i];
            zn[r][4 * i + 0] = v.x; zn[r][4 * i + 1] = v.y;
            zn[r][4 * i + 2] = v.z; zn[r][4 * i + 3] = v.w;
        }
    }

    float c[8];
    #pragma unroll
    for (int r = 0; r < 8; ++r) c[r] = 0.f;

    for (int mj = 0; mj < NN; mj += 64) {
        int m = mj + lane;
        const float4* zmp = reinterpret_cast<const float4*>(Zb + (size_t)m * HH);
        float zm[HH];
        #pragma unroll
        for (int i = 0; i < HH / 4; ++i)
            *reinterpret_cast<float4*>(&zm[4 * i]) = zmp[i];
        float lm = lse[(size_t)b * NN + m];

        #pragma unroll
        for (int r = 0; r < 8; ++r) {
            float a = 0.f;
            #pragma unroll
            for (int h = 0; h < HH; ++h) a += zn[r][h] * zm[h];
            c[r] += __expf(a - lm);          // S[m, n0+r]
        }
    }

    #pragma unroll
    for (int off = 1; off < 64; off <<= 1) {
        #pragma unroll
        for (int r = 0; r < 8; ++r)
            c[r] += __shfl_xor(c[r], off, 64);
    }
    if (lane == 0) {
        #pragma unroll
        for (int r = 0; r < 8; ++r)
            dinv[(size_t)b * NN + n0 + r] = rsqrtf(1.5f + 0.5f * c[r]);
    }
}

// ---------------- kernel 4: final output, 4 m per lane via b128 ----------------
#define RB 16
#define K4C 256
__global__ __launch_bounds__(256) void k_out(
    const float* __restrict__ Z, const float* __restrict__ Zt,
    const float* __restrict__ lse, const float* __restrict__ dinv,
    float* __restrict__ out) {
    __shared__ float Zs[HH][K4C];
    __shared__ float lseS[K4C], dvS[K4C];

    int t = threadIdx.x, lane = t & 63, w = t >> 6;
    int b = blockIdx.y;
    int n0 = blockIdx.x * RB;

    float zn[4][HH];
    float lse_n[4], dv_n[4];
    int nrow[4];
    #pragma unroll
    for (int r = 0; r < 4; ++r) {
        int n = n0 + w * 4 + r;
        nrow[r] = n;
        const float* zr = Z + ((size_t)b * NN + n) * HH;
        #pragma unroll
        for (int i = 0; i < HH / 4; ++i) {
            float4 v = reinterpret_cast<const float4*>(zr)[i];
            zn[r][4 * i + 0] = v.x; zn[r][4 * i + 1] = v.y;
            zn[r][4 * i + 2] = v.z; zn[r][4 * i + 3] = v.w;
        }
        lse_n[r] = lse[(size_t)b * NN + n] + LN2F;   // fold the 0.5
        dv_n[r]  = dinv[(size_t)b * NN + n];
    }

    for (int mc = 0; mc < NN; mc += K4C) {
        __syncthreads();
        for (int i = t; i < HH * K4C / 4; i += 256) {
            int h = i >> 6, p = i & 63;
            reinterpret_cast<float4*>(&Zs[h][0])[p] =
                reinterpret_cast<const float4*>(Zt + ((size_t)b * HH + h) * NN + mc)[p];
        }
        lseS[t] = lse[(size_t)b * NN + mc + t] + LN2F;
        dvS[t]  = dinv[(size_t)b * NN + mc + t];
        __syncthreads();

        int ml = lane * 4;
        int m0 = mc + ml;
        float4 lse4 = *reinterpret_cast<const float4*>(&lseS[ml]);
        float4 dv4  = *reinterpret_cast<const float4*>(&dvS[ml]);

        float acc[4][4];
        #pragma unroll
        for (int r = 0; r < 4; ++r)
            #pragma unroll
            for (int k = 0; k < 4; ++k) acc[r][k] = 0.f;

        #pragma unroll
        for (int h = 0; h < HH; ++h) {
            float4 zm = *reinterpret_cast<const float4*>(&Zs[h][ml]);
            #pragma unroll
            for (int r = 0; r < 4; ++r) {
                acc[r][0] += zn[r][h] * zm.x;
                acc[r][1] += zn[r][h] * zm.y;
                acc[r][2] += zn[r][h] * zm.z;
                acc[r][3] += zn[r][h] * zm.w;
            }
        }

        #pragma unroll
        for (int r = 0; r < 4; ++r) {
            float ln = lse_n[r], dn = dv_n[r];
            float4 o;
            o.x = __expf(acc[r][0] - ln) + __expf(acc[r][0] - lse4.x);
            o.y = __expf(acc[r][1] - ln) + __expf(acc[r][1] - lse4.y);
            o.z = __expf(acc[r][2] - ln) + __expf(acc[r][2] - lse4.z);
            o.w = __expf(acc[r][3] - ln) + __expf(acc[r][3] - lse4.w);
            if (nrow[r] == m0 + 0) o.x += 1.0f;
            if (nrow[r] == m0 + 1) o.y += 1.0f;
            if (nrow[r] == m0 + 2) o.z += 1.0f;
            if (nrow[r] == m0 + 3) o.w += 1.0f;
            o.x *= dn * dv4.x;
            o.y *= dn * dv4.y;
            o.z *= dn * dv4.z;
            o.w *= dn * dv4.w;
            *reinterpret_cast<float4*>(&out[((size_t)b * NN + nrow[r]) * NN + m0]) = o;
        }
    }
}

extern "C" void kernel_launch(void* const* d_in, const int* in_sizes, int n_in,
                              void* d_out, int out_size, void* d_ws, size_t ws_size,
                              hipStream_t stream) {
    const float* xt   = (const float*)d_in[0];
    const float* W    = (const float*)d_in[1];
    const float* bias = (const float*)d_in[2];
    float* out = (float*)d_out;
    float* ws  = (float*)d_ws;

    const size_t Z_OFF  = 0;
    const size_t ZT_OFF = Z_OFF  + (size_t)BB * NN * HH;
    const size_t LS_OFF = ZT_OFF + (size_t)BB * HH * NN;
    const size_t DV_OFF = LS_OFF + (size_t)BB * NN;

    float* Z    = ws + Z_OFF;
    float* Zt   = ws + ZT_OFF;
    float* lse  = ws + LS_OFF;
    float* dinv = ws + DV_OFF;

    k_z<<<dim3(BB * NN / 256), dim3(256), 0, stream>>>(xt, W, bias, Z, Zt);
    k_rowsum<<<dim3(NN / 32, BB), dim3(256), 0, stream>>>(Z, lse);
    k_colsum<<<dim3(NN / 32, BB), dim3(256), 0, stream>>>(Z, lse, dinv);
    k_out<<<dim3(NN / RB, BB), dim3(256), 0, stream>>>(Z, Zt, lse, dinv, out);
}